// Round 13
// baseline (230.206 us; speedup 1.0000x reference)
//
#include <hip/hip_runtime.h>
#include <cstdint>
#include <cmath>

#define THREADS 256
#define FLAT_G 1500      // 1500*1024 floats per sweep ≡ 0 (mod 6000): fixed cols per thread
#define RGROUPS 8

typedef float vf4 __attribute__((ext_vector_type(4)));

// ---------------- flat column-sum: perfectly linear global stream ------------
// Grid (FLAT_G, 2). Thread's float4 column index is invariant because the
// grid stride (FLAT_G*256 float4 = 1,536,000 floats) is a multiple of N.
// P[z][block][1024] holds per-block partials; one superblock = 256 rows.
template <bool WEIGHTED, bool NT>
__global__ __launch_bounds__(THREADS, 8)
void flat_colsum_kernel(const float* __restrict__ A0, const float* __restrict__ A1,
                        const float* __restrict__ w0, const float* __restrict__ w1,
                        float* __restrict__ P, int N, int totalF4) {
    const int z = blockIdx.y;
    const float* __restrict__ A = z ? A1 : A0;
    const float* __restrict__ wv = z ? w1 : w0;
    const vf4* __restrict__ A4 = (const vf4*)A;
    float* Pm = P + ((size_t)z * FLAT_G + blockIdx.x) * 1024;

    const int f4PerRow = N >> 2;                 // 1500
    const int stride = FLAT_G * THREADS;         // 384000 float4
    int i = blockIdx.x * THREADS + threadIdx.x;

    float ax = 0.f, ay = 0.f, az = 0.f, aw = 0.f;
    float bx = 0.f, by = 0.f, bz = 0.f, bw = 0.f;
    // 2-deep manual unroll; 23 waves/CU provide the rest of the MLP.
    for (; i + stride < totalF4; i += 2 * stride) {
        vf4 v0 = NT ? __builtin_nontemporal_load(A4 + i) : A4[i];
        vf4 v1 = NT ? __builtin_nontemporal_load(A4 + i + stride) : A4[i + stride];
        float q0 = 1.f, q1 = 1.f;
        if (WEIGHTED) {
            q0 = wv[i / f4PerRow];
            q1 = wv[(i + stride) / f4PerRow];
        }
        ax += q0 * v0.x; ay += q0 * v0.y; az += q0 * v0.z; aw += q0 * v0.w;
        bx += q1 * v1.x; by += q1 * v1.y; bz += q1 * v1.z; bw += q1 * v1.w;
    }
    if (i < totalF4) {
        vf4 v = NT ? __builtin_nontemporal_load(A4 + i) : A4[i];
        float q = WEIGHTED ? wv[i / f4PerRow] : 1.f;
        ax += q * v.x; ay += q * v.y; az += q * v.z; aw += q * v.w;
    }
    float4 o = {ax + bx, ay + by, az + bz, aw + bw};
    *reinterpret_cast<float4*>(&Pm[threadIdx.x * 4]) = o;
}

// ---------------- reduce flat partials -> out (2 outputs by z) ---------------
// Column j4 appears once per row-of-superblock: u4 = j4 + m*(N/4), m=0..255;
// block b = u4>>8, slot = u4&255. Scattered but small (12 MB, L2-resident).
__global__ void flat_reduce_kernel(const float* __restrict__ P,
                                   float* __restrict__ out0,
                                   float* __restrict__ out1,
                                   int N) {
    int j4 = blockIdx.x * THREADS + threadIdx.x;
    int f4PerRow = N >> 2;
    if (j4 >= f4PerRow) return;
    int z = blockIdx.y;
    float* out = z ? out1 : out0;
    const int rowsPerSuper = 256;
    int mchunk = rowsPerSuper / RGROUPS;        // 32
    int m0 = blockIdx.z * mchunk;

    float sx = 0.f, sy = 0.f, sz = 0.f, sw = 0.f;
    for (int m = m0; m < m0 + mchunk; ++m) {
        size_t u4 = (size_t)j4 + (size_t)m * f4PerRow;
        size_t b = u4 >> 8;
        int slot = (int)(u4 & 255);
        const float4 v = *reinterpret_cast<const float4*>(
            &P[((size_t)z * FLAT_G + b) * 1024 + slot * 4]);
        sx += v.x; sy += v.y; sz += v.z; sw += v.w;
    }
    atomicAdd(&out[j4 * 4 + 0], sx);
    atomicAdd(&out[j4 * 4 + 1], sy);
    atomicAdd(&out[j4 * 4 + 2], sz);
    atomicAdd(&out[j4 * 4 + 3], sw);
}

// ---------------- tiny feature reductions (4 units: s,p,q per input) ---------
__global__ void feat_all_kernel(const float* __restrict__ emb1, const float* __restrict__ emb2,
                                const float* __restrict__ eat1, const float* __restrict__ eat2,
                                const float* __restrict__ c1, const float* __restrict__ d1,
                                const float* __restrict__ c2, const float* __restrict__ d2,
                                const float* __restrict__ ce1, const float* __restrict__ ce2,
                                float* __restrict__ n1, float* __restrict__ n2,
                                float* __restrict__ eg1, float* __restrict__ eg2,
                                int Nn, int Ne) {
    int unit = blockIdx.y;
    const float *feat, *c, *d;
    float* out;
    int total, log2L;
    bool hasQ;
    if (unit == 0)      { feat = emb1; c = c1;  d = d1;      out = n1;  total = Nn * 32; log2L = 5; hasQ = true;  }
    else if (unit == 1) { feat = emb2; c = c2;  d = d2;      out = n2;  total = Nn * 32; log2L = 5; hasQ = true;  }
    else if (unit == 2) { feat = eat1; c = ce1; d = nullptr; out = eg1; total = Ne * 16; log2L = 4; hasQ = false; }
    else                { feat = eat2; c = ce2; d = nullptr; out = eg2; total = Ne * 16; log2L = 4; hasQ = false; }

    int stride = gridDim.x * blockDim.x;   // multiple of 32
    int idx = blockIdx.x * blockDim.x + threadIdx.x;
    int L = 1 << log2L;
    int l = idx & (L - 1);
    float as = 0.f, ap = 0.f, aq = 0.f;
    for (int i = idx; i < total; i += stride) {
        float v = feat[i];
        int r = i >> log2L;
        as += v;
        ap += c[r] * v;
        if (hasQ) aq += d[r] * v;
    }
    atomicAdd(&out[l], as);
    atomicAdd(&out[L + l], ap);
    if (hasQ) atomicAdd(&out[2 * L + l], aq);
}

// ---------------- scoring ----------------
__global__ void scoring_kernel(const float* __restrict__ Wn,
                               const float* __restrict__ We,
                               const float* __restrict__ n1,
                               const float* __restrict__ n2,
                               const float* __restrict__ eg1,
                               const float* __restrict__ eg2,
                               float* __restrict__ scoring) {
    int b = blockIdx.y;
    int chunk = blockIdx.x;
    const float *W, *e1, *e2;
    int total, log2D;
    if (b < 3) {
        W = Wn + (size_t)b * (64 * 64 * 16);
        e1 = n1 + (b == 2 ? 32 : 0);
        e2 = n2 + (b == 2 ? 32 : 0);
        total = 64 * 64 * 16;
        log2D = 6;
    } else {
        W = We; e1 = eg1; e2 = eg2;
        total = 32 * 32 * 16;
        log2D = 5;
    }
    int begin = chunk * 4096 + threadIdx.x;
    int end = (chunk + 1) * 4096;
    if (end > total) end = total;
    float acc = 0.f;
    for (int idx = begin; idx < end; idx += 256) {
        int de = idx >> 4;
        int e = de & ((1 << log2D) - 1);
        int dd = de >> log2D;
        acc += e1[dd] * e2[e] * W[idx];
    }
    __shared__ float red[256];
    red[threadIdx.x] = acc;
    __syncthreads();
    if (threadIdx.x < 16) {
        float s = 0.f;
        for (int t = threadIdx.x; t < 256; t += 16) s += red[t];
        atomicAdd(&scoring[b * 16 + threadIdx.x], s);
    }
}

// ---------------- final MLP head ----------------
__global__ void final_kernel(const float* __restrict__ scoring,
                             const float* __restrict__ n1,
                             const float* __restrict__ n2,
                             const float* __restrict__ eg1,
                             const float* __restrict__ eg2,
                             const float* __restrict__ Wbn,
                             const float* __restrict__ bn,
                             const float* __restrict__ Wbe,
                             const float* __restrict__ be,
                             const float* __restrict__ m1w, const float* __restrict__ m1b,
                             const float* __restrict__ m2w, const float* __restrict__ m2b,
                             const float* __restrict__ m3w, const float* __restrict__ m3b,
                             const float* __restrict__ sw, const float* __restrict__ sb,
                             const float* __restrict__ avg_v,
                             float* __restrict__ out) {
    __shared__ float sval[4][16];
    __shared__ float scores[4];
    int t = threadIdx.x;
    int b = t >> 4, k = t & 15;

    float blk;
    if (b < 3) {
        const float* e1 = n1 + (b == 2 ? 32 : 0);
        const float* e2 = n2 + (b == 2 ? 32 : 0);
        const float* wb = Wbn + (size_t)b * (16 * 128) + k * 128;
        float s = 0.f;
        for (int j = 0; j < 64; ++j) s += wb[j] * e1[j];
        for (int j = 0; j < 64; ++j) s += wb[64 + j] * e2[j];
        blk = s + bn[b * 16 + k];
    } else {
        const float* wb = Wbe + k * 64;
        float s = 0.f;
        for (int j = 0; j < 32; ++j) s += wb[j] * eg1[j];
        for (int j = 0; j < 32; ++j) s += wb[32 + j] * eg2[j];
        blk = s + be[k];
    }
    float v = scoring[b * 16 + k] + blk;
    sval[b][k] = v > 0.f ? v : 0.f;
    __syncthreads();

    if (t < 4) {
        float h1[16], h2[8], h3[4];
        for (int o = 0; o < 16; ++o) {
            float a = m1b[t * 16 + o];
            for (int i = 0; i < 16; ++i) a += m1w[(t * 16 + o) * 16 + i] * sval[t][i];
            h1[o] = a > 0.f ? a : 0.f;
        }
        for (int o = 0; o < 8; ++o) {
            float a = m2b[t * 8 + o];
            for (int i = 0; i < 16; ++i) a += m2w[(t * 8 + o) * 16 + i] * h1[i];
            h2[o] = a > 0.f ? a : 0.f;
        }
        for (int o = 0; o < 4; ++o) {
            float a = m3b[t * 4 + o];
            for (int i = 0; i < 8; ++i) a += m3w[(t * 4 + o) * 8 + i] * h2[i];
            h3[o] = a > 0.f ? a : 0.f;
        }
        float z = sb[t];
        for (int i = 0; i < 4; ++i) z += sw[t * 4 + i] * h3[i];
        scores[t] = 1.0f / (1.0f + expf(-z));
    }
    __syncthreads();

    if (t == 0) {
        const int ord[4] = {0, 1, 3, 2};
        float av = avg_v[0];
        float acc = 0.f;
        for (int j = 0; j < 4; ++j) {
            float sc = scores[ord[j]];
            out[2 + j] = sc;
            acc += -logf(sc);
        }
        float ged = acc * av;
        out[1] = ged;
        out[0] = expf(-ged / av);
    }
}

extern "C" void kernel_launch(void* const* d_in, const int* in_sizes, int n_in,
                              void* d_out, int out_size, void* d_ws, size_t ws_size,
                              hipStream_t stream) {
    const float* emb1  = (const float*)d_in[0];
    const float* emb2  = (const float*)d_in[1];
    const float* adj1  = (const float*)d_in[2];
    const float* adj2  = (const float*)d_in[3];
    const float* eat1  = (const float*)d_in[4];
    const float* eat2  = (const float*)d_in[5];
    const float* eadj1 = (const float*)d_in[6];
    const float* eadj2 = (const float*)d_in[7];
    const float* avg_v = (const float*)d_in[8];
    const float* Wn    = (const float*)d_in[9];
    const float* Wbn   = (const float*)d_in[10];
    const float* bn    = (const float*)d_in[11];
    const float* We    = (const float*)d_in[12];
    const float* Wbe   = (const float*)d_in[13];
    const float* be    = (const float*)d_in[14];
    const float* m1w   = (const float*)d_in[15];
    const float* m1b   = (const float*)d_in[16];
    const float* m2w   = (const float*)d_in[17];
    const float* m2b   = (const float*)d_in[18];
    const float* m3w   = (const float*)d_in[19];
    const float* m3b   = (const float*)d_in[20];
    const float* sw    = (const float*)d_in[21];
    const float* sb    = (const float*)d_in[22];

    int Nn = in_sizes[0] / 32;   // 6000
    int Ne = in_sizes[4] / 16;   // 6000
    int N  = Nn;
    int totalF4 = (N / 4) * N;   // 9,000,000

    float* ws  = (float*)d_ws;
    float* P   = ws;                              // [2][FLAT_G][1024] = 12.3 MB
    float* c1  = P + (size_t)2 * FLAT_G * 1024;
    float* c2  = c1 + N;
    float* ce1 = c2 + N;
    float* ce2 = ce1 + N;
    float* d1  = ce2 + N;
    float* d2  = d1 + N;
    float* n1  = d2 + N;       // [s(32), p(32), q(32)]
    float* n2  = n1 + 96;
    float* eg1 = n2 + 96;      // [s(16), p(16)]
    float* eg2 = eg1 + 32;
    float* scoring = eg2 + 32; // [4][16]
    hipMemsetAsync(c1, 0, (6 * (size_t)N + 320) * sizeof(float), stream);

    dim3 blk(THREADS);
    dim3 gridF(FLAT_G, 2);
    dim3 gridR((N / 4 + THREADS - 1) / THREADS, 2, RGROUPS);   // 6 x 2 x 8

    // 1) edge colsums: linear nt stream (keep L3 for adj)
    flat_colsum_kernel<false, true><<<gridF, blk, 0, stream>>>(
        eadj1, eadj2, nullptr, nullptr, P, N, totalF4);
    flat_reduce_kernel<<<gridR, blk, 0, stream>>>(P, ce1, ce2, N);
    // 2) node colsums: linear stream, L3-allocating
    flat_colsum_kernel<false, false><<<gridF, blk, 0, stream>>>(
        adj1, adj2, nullptr, nullptr, P, N, totalF4);
    flat_reduce_kernel<<<gridR, blk, 0, stream>>>(P, c1, c2, N);
    // 3) weighted: d = A^T c, adj partially L3-resident from step 2
    flat_colsum_kernel<true, false><<<gridF, blk, 0, stream>>>(
        adj1, adj2, c1, c2, P, N, totalF4);
    flat_reduce_kernel<<<gridR, blk, 0, stream>>>(P, d1, d2, N);
    // 4) pooled vectors: s, p = c^T feat, q = d^T feat
    feat_all_kernel<<<dim3(16, 4), blk, 0, stream>>>(emb1, emb2, eat1, eat2,
                                                     c1, d1, c2, d2, ce1, ce2,
                                                     n1, n2, eg1, eg2, Nn, Ne);
    // 5) bilinear scoring
    scoring_kernel<<<dim3(16, 4), blk, 0, stream>>>(Wn, We, n1, n2, eg1, eg2, scoring);
    // 6) MLP head
    final_kernel<<<1, 64, 0, stream>>>(scoring, n1, n2, eg1, eg2,
                                       Wbn, bn, Wbe, be,
                                       m1w, m1b, m2w, m2b, m3w, m3b, sw, sb,
                                       avg_v, (float*)d_out);
}

// Round 14
// 207.521 us; speedup vs baseline: 1.1093x; 1.1093x over previous
//
#include <hip/hip_runtime.h>
#include <cstdint>
#include <cmath>

#define THREADS 256
#define LDP 6016
#define RGROUPS 8
#define SLAB_R 64        // rows per slab -> 94 slabs

typedef float vf4 __attribute__((ext_vector_type(4)));

// ---------------- unweighted colsum over FOUR matrices ----------------
// z: 0=eadj1(nt), 1=eadj2(nt), 2=adj1, 3=adj2. nt keeps single-use edge data
// out of L3 so adj stays resident for the weighted pass.
__global__ __launch_bounds__(THREADS, 8)
void colsum4_kernel(const float* __restrict__ M0, const float* __restrict__ M1,
                    const float* __restrict__ M2, const float* __restrict__ M3,
                    float* __restrict__ P, int N, int nSlabs, int R) {
    const int z = blockIdx.z;
    const float* __restrict__ A = (z == 0) ? M0 : (z == 1) ? M1 : (z == 2) ? M2 : M3;
    const int col = blockIdx.x * (THREADS * 4) + threadIdx.x * 4;
    if (col >= N) return;
    const int slab = blockIdx.y;
    int r0 = slab * R;
    int r1 = r0 + R;
    if (r1 > N) r1 = N;

    float ax = 0.f, ay = 0.f, az = 0.f, aw = 0.f;
    float bx = 0.f, by = 0.f, bz = 0.f, bw = 0.f;
    const float* p = A + (size_t)r0 * N + col;
    const size_t sN = (size_t)N;
    int r = r0;
    if (z < 2) {
        for (; r + 8 <= r1; r += 8, p += 8 * sN) {
            vf4 v0 = __builtin_nontemporal_load((const vf4*)(p + 0 * sN));
            vf4 v1 = __builtin_nontemporal_load((const vf4*)(p + 1 * sN));
            vf4 v2 = __builtin_nontemporal_load((const vf4*)(p + 2 * sN));
            vf4 v3 = __builtin_nontemporal_load((const vf4*)(p + 3 * sN));
            vf4 v4 = __builtin_nontemporal_load((const vf4*)(p + 4 * sN));
            vf4 v5 = __builtin_nontemporal_load((const vf4*)(p + 5 * sN));
            vf4 v6 = __builtin_nontemporal_load((const vf4*)(p + 6 * sN));
            vf4 v7 = __builtin_nontemporal_load((const vf4*)(p + 7 * sN));
            ax += v0.x; ay += v0.y; az += v0.z; aw += v0.w;
            bx += v1.x; by += v1.y; bz += v1.z; bw += v1.w;
            ax += v2.x; ay += v2.y; az += v2.z; aw += v2.w;
            bx += v3.x; by += v3.y; bz += v3.z; bw += v3.w;
            ax += v4.x; ay += v4.y; az += v4.z; aw += v4.w;
            bx += v5.x; by += v5.y; bz += v5.z; bw += v5.w;
            ax += v6.x; ay += v6.y; az += v6.z; aw += v6.w;
            bx += v7.x; by += v7.y; bz += v7.z; bw += v7.w;
        }
    } else {
        for (; r + 8 <= r1; r += 8, p += 8 * sN) {
            vf4 v0 = *(const vf4*)(p + 0 * sN);
            vf4 v1 = *(const vf4*)(p + 1 * sN);
            vf4 v2 = *(const vf4*)(p + 2 * sN);
            vf4 v3 = *(const vf4*)(p + 3 * sN);
            vf4 v4 = *(const vf4*)(p + 4 * sN);
            vf4 v5 = *(const vf4*)(p + 5 * sN);
            vf4 v6 = *(const vf4*)(p + 6 * sN);
            vf4 v7 = *(const vf4*)(p + 7 * sN);
            ax += v0.x; ay += v0.y; az += v0.z; aw += v0.w;
            bx += v1.x; by += v1.y; bz += v1.z; bw += v1.w;
            ax += v2.x; ay += v2.y; az += v2.z; aw += v2.w;
            bx += v3.x; by += v3.y; bz += v3.z; bw += v3.w;
            ax += v4.x; ay += v4.y; az += v4.z; aw += v4.w;
            bx += v5.x; by += v5.y; bz += v5.z; bw += v5.w;
            ax += v6.x; ay += v6.y; az += v6.z; aw += v6.w;
            bx += v7.x; by += v7.y; bz += v7.z; bw += v7.w;
        }
    }
    for (; r < r1; ++r, p += sN) {
        vf4 v = *(const vf4*)(p);
        ax += v.x; ay += v.y; az += v.z; aw += v.w;
    }
    float4 o = {ax + bx, ay + by, az + bz, aw + bw};
    *reinterpret_cast<float4*>(&P[((size_t)z * nSlabs + slab) * LDP + col]) = o;
}

// ---------------- weighted colsum over TWO matrices (d = A^T c) --------------
__global__ __launch_bounds__(THREADS, 8)
void colsum2w_kernel(const float* __restrict__ A0, const float* __restrict__ A1,
                     const float* __restrict__ w0, const float* __restrict__ w1,
                     float* __restrict__ P, int N, int nSlabs, int R) {
    const int z = blockIdx.z;
    const float* __restrict__ A = z ? A1 : A0;
    const float* __restrict__ wv = z ? w1 : w0;
    const int col = blockIdx.x * (THREADS * 4) + threadIdx.x * 4;
    if (col >= N) return;
    const int slab = blockIdx.y;
    int r0 = slab * R;
    int r1 = r0 + R;
    if (r1 > N) r1 = N;

    float ax = 0.f, ay = 0.f, az = 0.f, aw = 0.f;
    float bx = 0.f, by = 0.f, bz = 0.f, bw = 0.f;
    const float* p = A + (size_t)r0 * N + col;
    const size_t sN = (size_t)N;
    int r = r0;
    for (; r + 8 <= r1; r += 8, p += 8 * sN) {
        vf4 v0 = *(const vf4*)(p + 0 * sN);
        vf4 v1 = *(const vf4*)(p + 1 * sN);
        vf4 v2 = *(const vf4*)(p + 2 * sN);
        vf4 v3 = *(const vf4*)(p + 3 * sN);
        vf4 v4 = *(const vf4*)(p + 4 * sN);
        vf4 v5 = *(const vf4*)(p + 5 * sN);
        vf4 v6 = *(const vf4*)(p + 6 * sN);
        vf4 v7 = *(const vf4*)(p + 7 * sN);
        float q0 = wv[r + 0], q1 = wv[r + 1], q2 = wv[r + 2], q3 = wv[r + 3];
        float q4 = wv[r + 4], q5 = wv[r + 5], q6 = wv[r + 6], q7 = wv[r + 7];
        ax += q0 * v0.x; ay += q0 * v0.y; az += q0 * v0.z; aw += q0 * v0.w;
        bx += q1 * v1.x; by += q1 * v1.y; bz += q1 * v1.z; bw += q1 * v1.w;
        ax += q2 * v2.x; ay += q2 * v2.y; az += q2 * v2.z; aw += q2 * v2.w;
        bx += q3 * v3.x; by += q3 * v3.y; bz += q3 * v3.z; bw += q3 * v3.w;
        ax += q4 * v4.x; ay += q4 * v4.y; az += q4 * v4.z; aw += q4 * v4.w;
        bx += q5 * v5.x; by += q5 * v5.y; bz += q5 * v5.z; bw += q5 * v5.w;
        ax += q6 * v6.x; ay += q6 * v6.y; az += q6 * v6.z; aw += q6 * v6.w;
        bx += q7 * v7.x; by += q7 * v7.y; bz += q7 * v7.z; bw += q7 * v7.w;
    }
    for (; r < r1; ++r, p += sN) {
        vf4 v = *(const vf4*)(p);
        float q = wv[r];
        ax += q * v.x; ay += q * v.y; az += q * v.z; aw += q * v.w;
    }
    float4 o = {ax + bx, ay + by, az + bz, aw + bw};
    *reinterpret_cast<float4*>(&P[((size_t)z * nSlabs + slab) * LDP + col]) = o;
}

// ---------------- reduce partials over slabs; out selected by z --------------
__global__ void reduce4_kernel(const float* __restrict__ P,
                               float* __restrict__ o0, float* __restrict__ o1,
                               float* __restrict__ o2, float* __restrict__ o3,
                               int N, int nSlabs) {
    int col = blockIdx.x * (THREADS * 4) + threadIdx.x * 4;
    if (col >= N) return;
    int z = blockIdx.y;
    float* out = (z == 0) ? o0 : (z == 1) ? o1 : (z == 2) ? o2 : o3;
    int chunk = (nSlabs + RGROUPS - 1) / RGROUPS;
    int i0 = blockIdx.z * chunk;
    int i1 = i0 + chunk;
    if (i1 > nSlabs) i1 = nSlabs;

    const float* p = P + ((size_t)z * nSlabs + i0) * LDP + col;
    float4 s0 = {0, 0, 0, 0}, s1 = {0, 0, 0, 0};
    int i = i0;
    for (; i + 2 <= i1; i += 2, p += 2 * LDP) {
        float4 a = *reinterpret_cast<const float4*>(p);
        float4 b = *reinterpret_cast<const float4*>(p + LDP);
        s0.x += a.x; s0.y += a.y; s0.z += a.z; s0.w += a.w;
        s1.x += b.x; s1.y += b.y; s1.z += b.z; s1.w += b.w;
    }
    if (i < i1) {
        float4 a = *reinterpret_cast<const float4*>(p);
        s0.x += a.x; s0.y += a.y; s0.z += a.z; s0.w += a.w;
    }
    atomicAdd(&out[col + 0], s0.x + s1.x);
    atomicAdd(&out[col + 1], s0.y + s1.y);
    atomicAdd(&out[col + 2], s0.z + s1.z);
    atomicAdd(&out[col + 3], s0.w + s1.w);
}

// ---------------- tiny feature reductions (4 units: s,p,q per input) ---------
__global__ void feat_all_kernel(const float* __restrict__ emb1, const float* __restrict__ emb2,
                                const float* __restrict__ eat1, const float* __restrict__ eat2,
                                const float* __restrict__ c1, const float* __restrict__ d1,
                                const float* __restrict__ c2, const float* __restrict__ d2,
                                const float* __restrict__ ce1, const float* __restrict__ ce2,
                                float* __restrict__ n1, float* __restrict__ n2,
                                float* __restrict__ eg1, float* __restrict__ eg2,
                                int Nn, int Ne) {
    int unit = blockIdx.y;
    const float *feat, *c, *d;
    float* out;
    int total, log2L;
    bool hasQ;
    if (unit == 0)      { feat = emb1; c = c1;  d = d1;      out = n1;  total = Nn * 32; log2L = 5; hasQ = true;  }
    else if (unit == 1) { feat = emb2; c = c2;  d = d2;      out = n2;  total = Nn * 32; log2L = 5; hasQ = true;  }
    else if (unit == 2) { feat = eat1; c = ce1; d = nullptr; out = eg1; total = Ne * 16; log2L = 4; hasQ = false; }
    else                { feat = eat2; c = ce2; d = nullptr; out = eg2; total = Ne * 16; log2L = 4; hasQ = false; }

    int stride = gridDim.x * blockDim.x;   // multiple of 32
    int idx = blockIdx.x * blockDim.x + threadIdx.x;
    int L = 1 << log2L;
    int l = idx & (L - 1);
    float as = 0.f, ap = 0.f, aq = 0.f;
    for (int i = idx; i < total; i += stride) {
        float v = feat[i];
        int r = i >> log2L;
        as += v;
        ap += c[r] * v;
        if (hasQ) aq += d[r] * v;
    }
    atomicAdd(&out[l], as);
    atomicAdd(&out[L + l], ap);
    if (hasQ) atomicAdd(&out[2 * L + l], aq);
}

// ---------------- scoring ----------------
__global__ void scoring_kernel(const float* __restrict__ Wn,
                               const float* __restrict__ We,
                               const float* __restrict__ n1,
                               const float* __restrict__ n2,
                               const float* __restrict__ eg1,
                               const float* __restrict__ eg2,
                               float* __restrict__ scoring) {
    int b = blockIdx.y;
    int chunk = blockIdx.x;
    const float *W, *e1, *e2;
    int total, log2D;
    if (b < 3) {
        W = Wn + (size_t)b * (64 * 64 * 16);
        e1 = n1 + (b == 2 ? 32 : 0);
        e2 = n2 + (b == 2 ? 32 : 0);
        total = 64 * 64 * 16;
        log2D = 6;
    } else {
        W = We; e1 = eg1; e2 = eg2;
        total = 32 * 32 * 16;
        log2D = 5;
    }
    int begin = chunk * 4096 + threadIdx.x;
    int end = (chunk + 1) * 4096;
    if (end > total) end = total;
    float acc = 0.f;
    for (int idx = begin; idx < end; idx += 256) {
        int de = idx >> 4;
        int e = de & ((1 << log2D) - 1);
        int dd = de >> log2D;
        acc += e1[dd] * e2[e] * W[idx];
    }
    __shared__ float red[256];
    red[threadIdx.x] = acc;
    __syncthreads();
    if (threadIdx.x < 16) {
        float s = 0.f;
        for (int t = threadIdx.x; t < 256; t += 16) s += red[t];
        atomicAdd(&scoring[b * 16 + threadIdx.x], s);
    }
}

// ---------------- final MLP head ----------------
__global__ void final_kernel(const float* __restrict__ scoring,
                             const float* __restrict__ n1,
                             const float* __restrict__ n2,
                             const float* __restrict__ eg1,
                             const float* __restrict__ eg2,
                             const float* __restrict__ Wbn,
                             const float* __restrict__ bn,
                             const float* __restrict__ Wbe,
                             const float* __restrict__ be,
                             const float* __restrict__ m1w, const float* __restrict__ m1b,
                             const float* __restrict__ m2w, const float* __restrict__ m2b,
                             const float* __restrict__ m3w, const float* __restrict__ m3b,
                             const float* __restrict__ sw, const float* __restrict__ sb,
                             const float* __restrict__ avg_v,
                             float* __restrict__ out) {
    __shared__ float sval[4][16];
    __shared__ float scores[4];
    int t = threadIdx.x;
    int b = t >> 4, k = t & 15;

    float blk;
    if (b < 3) {
        const float* e1 = n1 + (b == 2 ? 32 : 0);
        const float* e2 = n2 + (b == 2 ? 32 : 0);
        const float* wb = Wbn + (size_t)b * (16 * 128) + k * 128;
        float s = 0.f;
        for (int j = 0; j < 64; ++j) s += wb[j] * e1[j];
        for (int j = 0; j < 64; ++j) s += wb[64 + j] * e2[j];
        blk = s + bn[b * 16 + k];
    } else {
        const float* wb = Wbe + k * 64;
        float s = 0.f;
        for (int j = 0; j < 32; ++j) s += wb[j] * eg1[j];
        for (int j = 0; j < 32; ++j) s += wb[32 + j] * eg2[j];
        blk = s + be[k];
    }
    float v = scoring[b * 16 + k] + blk;
    sval[b][k] = v > 0.f ? v : 0.f;
    __syncthreads();

    if (t < 4) {
        float h1[16], h2[8], h3[4];
        for (int o = 0; o < 16; ++o) {
            float a = m1b[t * 16 + o];
            for (int i = 0; i < 16; ++i) a += m1w[(t * 16 + o) * 16 + i] * sval[t][i];
            h1[o] = a > 0.f ? a : 0.f;
        }
        for (int o = 0; o < 8; ++o) {
            float a = m2b[t * 8 + o];
            for (int i = 0; i < 16; ++i) a += m2w[(t * 8 + o) * 16 + i] * h1[i];
            h2[o] = a > 0.f ? a : 0.f;
        }
        for (int o = 0; o < 4; ++o) {
            float a = m3b[t * 4 + o];
            for (int i = 0; i < 8; ++i) a += m3w[(t * 4 + o) * 8 + i] * h2[i];
            h3[o] = a > 0.f ? a : 0.f;
        }
        float z = sb[t];
        for (int i = 0; i < 4; ++i) z += sw[t * 4 + i] * h3[i];
        scores[t] = 1.0f / (1.0f + expf(-z));
    }
    __syncthreads();

    if (t == 0) {
        const int ord[4] = {0, 1, 3, 2};
        float av = avg_v[0];
        float acc = 0.f;
        for (int j = 0; j < 4; ++j) {
            float sc = scores[ord[j]];
            out[2 + j] = sc;
            acc += -logf(sc);
        }
        float ged = acc * av;
        out[1] = ged;
        out[0] = expf(-ged / av);
    }
}

extern "C" void kernel_launch(void* const* d_in, const int* in_sizes, int n_in,
                              void* d_out, int out_size, void* d_ws, size_t ws_size,
                              hipStream_t stream) {
    const float* emb1  = (const float*)d_in[0];
    const float* emb2  = (const float*)d_in[1];
    const float* adj1  = (const float*)d_in[2];
    const float* adj2  = (const float*)d_in[3];
    const float* eat1  = (const float*)d_in[4];
    const float* eat2  = (const float*)d_in[5];
    const float* eadj1 = (const float*)d_in[6];
    const float* eadj2 = (const float*)d_in[7];
    const float* avg_v = (const float*)d_in[8];
    const float* Wn    = (const float*)d_in[9];
    const float* Wbn   = (const float*)d_in[10];
    const float* bn    = (const float*)d_in[11];
    const float* We    = (const float*)d_in[12];
    const float* Wbe   = (const float*)d_in[13];
    const float* be    = (const float*)d_in[14];
    const float* m1w   = (const float*)d_in[15];
    const float* m1b   = (const float*)d_in[16];
    const float* m2w   = (const float*)d_in[17];
    const float* m2b   = (const float*)d_in[18];
    const float* m3w   = (const float*)d_in[19];
    const float* m3b   = (const float*)d_in[20];
    const float* sw    = (const float*)d_in[21];
    const float* sb    = (const float*)d_in[22];

    int Nn = in_sizes[0] / 32;   // 6000
    int Ne = in_sizes[4] / 16;   // 6000
    int N  = Nn;

    int nSlabs = (N + SLAB_R - 1) / SLAB_R;    // 94

    float* ws  = (float*)d_ws;
    float* P   = ws;                            // [4][nSlabs][LDP]
    float* c1  = P + (size_t)4 * nSlabs * LDP;
    float* c2  = c1 + N;
    float* ce1 = c2 + N;
    float* ce2 = ce1 + N;
    float* d1  = ce2 + N;
    float* d2  = d1 + N;
    float* n1  = d2 + N;       // [s(32), p(32), q(32)]
    float* n2  = n1 + 96;
    float* eg1 = n2 + 96;      // [s(16), p(16)]
    float* eg2 = eg1 + 32;
    float* scoring = eg2 + 32; // [4][16]
    // zero all atomically-accumulated outputs: c1..d2 (6N) + tail (320)
    hipMemsetAsync(c1, 0, (6 * (size_t)N + 320) * sizeof(float), stream);

    dim3 blk(THREADS);
    int colChunks = (N + THREADS * 4 - 1) / (THREADS * 4);   // 6

    // 1) unweighted colsums of ALL FOUR matrices (eadj via nt loads -> L3 holds adj)
    colsum4_kernel<<<dim3(colChunks, nSlabs, 4), blk, 0, stream>>>(
        eadj1, eadj2, adj1, adj2, P, N, nSlabs, SLAB_R);
    // 2) reduce -> ce1, ce2, c1, c2
    reduce4_kernel<<<dim3(colChunks, 4, RGROUPS), blk, 0, stream>>>(
        P, ce1, ce2, c1, c2, N, nSlabs);
    // 3) weighted colsums d = A^T c (adj L3-resident)
    colsum2w_kernel<<<dim3(colChunks, nSlabs, 2), blk, 0, stream>>>(
        adj1, adj2, c1, c2, P, N, nSlabs, SLAB_R);
    // 4) reduce -> d1, d2
    reduce4_kernel<<<dim3(colChunks, 2, RGROUPS), blk, 0, stream>>>(
        P, d1, d2, d1, d2, N, nSlabs);
    // 5) pooled vectors: s, p = c^T feat, q = d^T feat
    feat_all_kernel<<<dim3(16, 4), blk, 0, stream>>>(emb1, emb2, eat1, eat2,
                                                     c1, d1, c2, d2, ce1, ce2,
                                                     n1, n2, eg1, eg2, Nn, Ne);
    // 6) bilinear scoring
    scoring_kernel<<<dim3(16, 4), blk, 0, stream>>>(Wn, We, n1, n2, eg1, eg2, scoring);
    // 7) MLP head
    final_kernel<<<1, 64, 0, stream>>>(scoring, n1, n2, eg1, eg2,
                                       Wbn, bn, Wbe, be,
                                       m1w, m1b, m2w, m2b, m3w, m3b, sw, sb,
                                       avg_v, (float*)d_out);
}